// Round 4
// baseline (307.876 us; speedup 1.0000x reference)
//
#include <hip/hip_runtime.h>
#include <hip/hip_bf16.h>

typedef float floatx4 __attribute__((ext_vector_type(4)));
typedef short shortx8 __attribute__((ext_vector_type(8)));
typedef short shortx4 __attribute__((ext_vector_type(4)));

#define CFENCE() asm volatile("" ::: "memory")

__device__ __forceinline__ float bf2f(short s) {
    union { unsigned u; float f; } cv;
    cv.u = ((unsigned)(unsigned short)s) << 16;
    return cv.f;
}
__device__ __forceinline__ short f2bf(float f) {
    union { float f; unsigned u; } cv; cv.f = f;
    unsigned r = (cv.u + 0x7fffu + ((cv.u >> 16) & 1u)) >> 16;
    return (short)r;
}

// ---------------- K0a: weight transpose + bf16 convert ----------------
__global__ __launch_bounds__(256) void wtrans(const float* __restrict__ Wq,
                                              const float* __restrict__ Wk,
                                              const float* __restrict__ Wv,
                                              const float* __restrict__ Wo,
                                              short* __restrict__ wqkv_t,
                                              short* __restrict__ wo_t) {
    __shared__ float tile[32][33];
    int z = blockIdx.z;
    const float* src = (z == 0) ? Wq : (z == 1) ? Wk : (z == 2) ? Wv : Wo;
    int n0 = blockIdx.x * 32, k0 = blockIdx.y * 32;
    for (int p = threadIdx.y; p < 32; p += 8)
        tile[p][threadIdx.x] = src[(size_t)(k0 + p) * 256 + n0 + threadIdx.x];
    __syncthreads();
    for (int p = threadIdx.y; p < 32; p += 8) {
        int n = n0 + p, k = k0 + threadIdx.x;
        short b = f2bf(tile[threadIdx.x][p]);
        if (z < 3) wqkv_t[(size_t)(z * 256 + n) * 256 + k] = b;
        else       wo_t[(size_t)n * 256 + k] = b;
    }
}

// ---------------- K0b: CPB MLP, one block per table entry ----------------
__device__ __forceinline__ float sgnlog(float x) {
    return copysignf(__log2f(fabsf(x) + 1.f) / 3.f, x);
}
__global__ __launch_bounds__(256) void bias_mlp(const float* __restrict__ ls,
                                                const float* __restrict__ w1,
                                                const float* __restrict__ b1,
                                                const float* __restrict__ w2,
                                                float* __restrict__ b225g,
                                                float* __restrict__ scaleOut) {
    int e = blockIdx.x;
    int tid = threadIdx.x, lane = tid & 63, wid = tid >> 6;
    if (e == 0 && tid < 8) scaleOut[tid] = expf(fminf(ls[tid], 4.6051701859880914f));
    int dh = e / 15 - 7, dw = e % 15 - 7;
    float t0 = sgnlog(8.f * (float)dh / 7.f);
    float t1 = sgnlog(8.f * (float)dw / 7.f);
    float acc[8];
#pragma unroll
    for (int j = 0; j < 8; ++j) acc[j] = 0.f;
#pragma unroll
    for (int s = 0; s < 2; ++s) {
        int hsm = tid + s * 256;
        float hid = fmaxf(0.f, t0 * w1[hsm] + t1 * w1[512 + hsm] + b1[hsm]);
#pragma unroll
        for (int j = 0; j < 8; ++j) acc[j] += hid * w2[hsm * 8 + j];
    }
#pragma unroll
    for (int off = 1; off < 64; off <<= 1)
#pragma unroll
        for (int j = 0; j < 8; ++j) acc[j] += __shfl_xor(acc[j], off, 64);
    __shared__ float red[4][8];
    if (lane == 0)
#pragma unroll
        for (int j = 0; j < 8; ++j) red[wid][j] = acc[j];
    __syncthreads();
    if (tid < 8)
        b225g[e * 8 + tid] = red[0][tid] + red[1][tid] + red[2][tid] + red[3][tid];
}

// ---------------- K0c: expand to per-head 64x64 bias ----------------
__global__ __launch_bounds__(256) void bias_expand(const float* __restrict__ b225g,
                                                   float* __restrict__ bias8) {
    int f = blockIdx.x * 256 + threadIdx.x;
    int h = f >> 12, ij = f & 4095, i = ij >> 6, j = ij & 63;
    int dh = (i >> 3) - (j >> 3), dw = (i & 7) - (j & 7);
    int e = (dh + 7) * 15 + (dw + 7);
    float v = b225g[e * 8 + h];
    bias8[f] = 16.f / (1.f + expf(-v));
}

// token row -> pixel (roll by +4 both ways, same map fwd/bwd)
__device__ __forceinline__ int row2pix(int row) {
    int w = row >> 6, t = row & 63;
    int b = w >> 6, wi = (w >> 3) & 7, wj = w & 7;
    int hh = (wi * 8 + (t >> 3) + 4) & 63;
    int ww = (wj * 8 + (t & 7) + 4) & 63;
    return (b * 64 + hh) * 64 + ww;
}

// ---------------- K1: QKV projection; A in LDS, B global->VGPR, 1 barrier ----------------
__global__ __launch_bounds__(256, 2) void qkv_gemm(const float* __restrict__ x,
                                                   const short* __restrict__ wt,
                                                   const float* __restrict__ bq,
                                                   const float* __restrict__ bk_,
                                                   const float* __restrict__ bv,
                                                   short* __restrict__ qkv) {
    __shared__ __align__(16) short As[128 * 264];
    int tid = threadIdx.x, lane = tid & 63, wid = tid >> 6;
    int quad = lane >> 4, l15 = lane & 15;
    int bm = blockIdx.x;

    // ---- stage A once: 128 rows x 256 k, fp32 gather -> bf16 LDS ----
    {
        int r = tid >> 1, half = tid & 1;
        const float* src = x + (size_t)row2pix(bm * 128 + r) * 256 + half * 128;
        short* dst = &As[r * 264 + half * 128];
#pragma unroll
        for (int g = 0; g < 4; ++g) {
            float4 v[8];
#pragma unroll
            for (int j = 0; j < 8; ++j) v[j] = *(const float4*)(src + g * 32 + j * 4);
#pragma unroll
            for (int j = 0; j < 4; ++j) {
                shortx8 s;
#pragma unroll
                for (int q2 = 0; q2 < 2; ++q2) {
                    float4 f = v[j * 2 + q2];
                    s[q2 * 4 + 0] = f2bf(f.x); s[q2 * 4 + 1] = f2bf(f.y);
                    s[q2 * 4 + 2] = f2bf(f.z); s[q2 * 4 + 3] = f2bf(f.w);
                }
                *(shortx8*)(dst + g * 32 + j * 8) = s;
            }
        }
    }

    int wm = (wid & 1) * 64, wn = (wid >> 1) * 64;
    // per-lane B fragment base: row = wn + nt*16 + l15, col chunk = quad*8
    const short* bbase[4];
#pragma unroll
    for (int nt = 0; nt < 4; ++nt)
        bbase[nt] = wt + (size_t)(wn + nt * 16 + l15) * 256 + quad * 8;

    // depth-2 pipeline over u = t*8 + kt  (offset = t*32768 + kt*32 shorts)
    shortx8 b0[4], b1[4];
#pragma unroll
    for (int nt = 0; nt < 4; ++nt) b0[nt] = *(const shortx8*)(bbase[nt] + 0);
#pragma unroll
    for (int nt = 0; nt < 4; ++nt) b1[nt] = *(const shortx8*)(bbase[nt] + 32);

    __syncthreads();  // A staged

    for (int t = 0; t < 6; ++t) {
        floatx4 acc[4][4];
#pragma unroll
        for (int mt = 0; mt < 4; ++mt)
#pragma unroll
            for (int nt = 0; nt < 4; ++nt) acc[mt][nt] = (floatx4){0.f, 0.f, 0.f, 0.f};
#pragma unroll
        for (int kt = 0; kt < 8; ++kt) {
            int u = t * 8 + kt + 2;
            shortx8 bn[4];
            if (u < 48) {
                int tn = u >> 3, kn = u & 7;
#pragma unroll
                for (int nt = 0; nt < 4; ++nt)
                    bn[nt] = *(const shortx8*)(bbase[nt] + tn * 32768 + kn * 32);
            }
            shortx8 af[4];
#pragma unroll
            for (int mt = 0; mt < 4; ++mt)
                af[mt] = *(const shortx8*)&As[(wm + mt * 16 + l15) * 264 + kt * 32 + quad * 8];
#pragma unroll
            for (int mt = 0; mt < 4; ++mt)
#pragma unroll
                for (int nt = 0; nt < 4; ++nt)
                    acc[mt][nt] = __builtin_amdgcn_mfma_f32_16x16x32_bf16(af[mt], b0[nt], acc[mt][nt], 0, 0, 0);
#pragma unroll
            for (int nt = 0; nt < 4; ++nt) { b0[nt] = b1[nt]; b1[nt] = bn[nt]; }
        }
        float biasv[4];
#pragma unroll
        for (int nt = 0; nt < 4; ++nt) {
            int col = t * 128 + wn + nt * 16 + l15;
            biasv[nt] = (col < 256) ? bq[col] : (col < 512) ? bk_[col - 256] : bv[col - 512];
        }
#pragma unroll
        for (int mt = 0; mt < 4; ++mt)
#pragma unroll
            for (int nt = 0; nt < 4; ++nt)
#pragma unroll
                for (int reg = 0; reg < 4; ++reg) {
                    int row = bm * 128 + wm + mt * 16 + quad * 4 + reg;
                    int col = t * 128 + wn + nt * 16 + l15;
                    qkv[(size_t)row * 768 + col] = f2bf(acc[mt][nt][reg] + biasv[nt]);
                }
    }
}

// ---------------- K3: per-window attention (wave-private LDS, no barriers) ----------------
__device__ __forceinline__ int regid(int t, int wi, int wj) {
    int a = (wi < 7) ? 0 : (((t >> 3) < 4) ? 1 : 2);
    int b = (wj < 7) ? 0 : (((t & 7) < 4) ? 1 : 2);
    return a * 3 + b;
}

__global__ __launch_bounds__(256, 2) void attn_kernel(const short* __restrict__ qkv,
                                                      const float* __restrict__ bias8,
                                                      const float* __restrict__ scale,
                                                      short* __restrict__ aout) {
    __shared__ __align__(16) short lds[4 * 8192];
    int tid = threadIdx.x, lane = tid & 63, wid = tid >> 6;
    int quad = lane >> 4, l15 = lane & 15;
    int win = blockIdx.x;
    int wi = (win >> 3) & 7, wj = win & 7;
    bool need_mask = (wi == 7) || (wj == 7);
    short* qn = &lds[wid * 8192];
    short* kn = qn + 3584;
    short* P = qn;
    short* vt = qn + 5632;

    for (int hi = 0; hi < 2; ++hi) {
        int h = wid + hi * 4;
        float sc = scale[h];
        const short* qp = qkv + (size_t)(win * 64 + lane) * 768 + h * 32;
        shortx8 qraw[4], kraw[4], vraw[4];
#pragma unroll
        for (int c2 = 0; c2 < 4; ++c2) {
            qraw[c2] = *(const shortx8*)(qp + c2 * 8);
            kraw[c2] = *(const shortx8*)(qp + 256 + c2 * 8);
            vraw[c2] = *(const shortx8*)(qp + 512 + c2 * 8);
        }
        float qs = 0.f, ks2 = 0.f;
#pragma unroll
        for (int c2 = 0; c2 < 4; ++c2)
#pragma unroll
            for (int j = 0; j < 8; ++j) {
                float f = bf2f(qraw[c2][j]); qs += f * f;
                float g = bf2f(kraw[c2][j]); ks2 += g * g;
            }
        float qr = sc / fmaxf(sqrtf(qs), 1e-12f);
        float kr = 1.f / fmaxf(sqrtf(ks2), 1e-12f);
        CFENCE();
#pragma unroll
        for (int c2 = 0; c2 < 4; ++c2) {
            shortx8 oq, ok;
#pragma unroll
            for (int j = 0; j < 8; ++j) {
                oq[j] = f2bf(bf2f(qraw[c2][j]) * qr);
                ok[j] = f2bf(bf2f(kraw[c2][j]) * kr);
            }
            *(shortx8*)&qn[lane * 56 + c2 * 8] = oq;
            *(shortx8*)&kn[lane * 56 + c2 * 8] = ok;
        }
        CFENCE();
        shortx8 aq[4], bkf[4];
#pragma unroll
        for (int mt = 0; mt < 4; ++mt)
            aq[mt] = *(const shortx8*)&qn[(mt * 16 + l15) * 56 + quad * 8];
#pragma unroll
        for (int nt = 0; nt < 4; ++nt)
            bkf[nt] = *(const shortx8*)&kn[(nt * 16 + l15) * 56 + quad * 8];
        floatx4 S[4][4];
#pragma unroll
        for (int mt = 0; mt < 4; ++mt)
#pragma unroll
            for (int nt = 0; nt < 4; ++nt) {
                floatx4 z = {0.f, 0.f, 0.f, 0.f};
                S[mt][nt] = __builtin_amdgcn_mfma_f32_16x16x32_bf16(aq[mt], bkf[nt], z, 0, 0, 0);
            }
        const float* bh = bias8 + (h << 12);
        float bound = sc + 16.5f;
        int jid[4];
        if (need_mask) {
#pragma unroll
            for (int nt = 0; nt < 4; ++nt) jid[nt] = regid(nt * 16 + l15, wi, wj);
        }
        float rs[4][4];
#pragma unroll
        for (int mt = 0; mt < 4; ++mt)
#pragma unroll
            for (int reg = 0; reg < 4; ++reg) {
                int i = mt * 16 + quad * 4 + reg;
                int iid = need_mask ? regid(i, wi, wj) : 0;
                float rowsum = 0.f;
#pragma unroll
                for (int nt = 0; nt < 4; ++nt) {
                    int j = nt * 16 + l15;
                    float v = S[mt][nt][reg] + bh[i * 64 + j];
                    if (need_mask && iid != jid[nt]) v -= 100.f;
                    float p = __expf(v - bound);
                    S[mt][nt][reg] = p;
                    rowsum += p;
                }
                rowsum += __shfl_xor(rowsum, 1, 64);
                rowsum += __shfl_xor(rowsum, 2, 64);
                rowsum += __shfl_xor(rowsum, 4, 64);
                rowsum += __shfl_xor(rowsum, 8, 64);
                rs[mt][reg] = 1.f / rowsum;
            }
        CFENCE();
#pragma unroll
        for (int mt = 0; mt < 4; ++mt)
#pragma unroll
            for (int nt = 0; nt < 4; ++nt)
#pragma unroll
                for (int reg = 0; reg < 4; ++reg)
                    P[(mt * 16 + quad * 4 + reg) * 88 + nt * 16 + l15] = f2bf(S[mt][nt][reg]);
#pragma unroll
        for (int c2 = 0; c2 < 4; ++c2)
#pragma unroll
            for (int j = 0; j < 8; ++j)
                vt[(c2 * 8 + j) * 72 + lane] = vraw[c2][j];
        CFENCE();
        floatx4 O[4][2];
#pragma unroll
        for (int mt = 0; mt < 4; ++mt)
#pragma unroll
            for (int nt = 0; nt < 2; ++nt) O[mt][nt] = (floatx4){0.f, 0.f, 0.f, 0.f};
#pragma unroll
        for (int ks = 0; ks < 2; ++ks) {
            shortx8 pa[4], vb[2];
#pragma unroll
            for (int mt = 0; mt < 4; ++mt)
                pa[mt] = *(const shortx8*)&P[(mt * 16 + l15) * 88 + ks * 32 + quad * 8];
#pragma unroll
            for (int nt = 0; nt < 2; ++nt)
                vb[nt] = *(const shortx8*)&vt[(nt * 16 + l15) * 72 + ks * 32 + quad * 8];
#pragma unroll
            for (int mt = 0; mt < 4; ++mt)
#pragma unroll
                for (int nt = 0; nt < 2; ++nt)
                    O[mt][nt] = __builtin_amdgcn_mfma_f32_16x16x32_bf16(pa[mt], vb[nt], O[mt][nt], 0, 0, 0);
        }
#pragma unroll
        for (int mt = 0; mt < 4; ++mt)
#pragma unroll
            for (int nt = 0; nt < 2; ++nt)
#pragma unroll
                for (int reg = 0; reg < 4; ++reg) {
                    int i = mt * 16 + quad * 4 + reg;
                    int d = nt * 16 + l15;
                    aout[(size_t)(win * 64 + i) * 256 + (h << 5) + d] =
                        f2bf(O[mt][nt][reg] * rs[mt][reg]);
                }
    }
}

// ---------------- K4: output projection; A in LDS, B global->VGPR, 1 barrier ----------------
__global__ __launch_bounds__(256, 2) void oproj_gemm(const short* __restrict__ ao,
                                                     const short* __restrict__ wot,
                                                     const float* __restrict__ bo,
                                                     float* __restrict__ out) {
    __shared__ __align__(16) short As[128 * 264];
    int tid = threadIdx.x, lane = tid & 63, wid = tid >> 6;
    int quad = lane >> 4, l15 = lane & 15;
    int bm = blockIdx.x;

    {
        int r = tid >> 1, half = tid & 1;
        const short* src = ao + (size_t)(bm * 128 + r) * 256 + half * 128;
        short* dst = &As[r * 264 + half * 128];
#pragma unroll
        for (int g = 0; g < 2; ++g) {
            shortx8 v[8];
#pragma unroll
            for (int j = 0; j < 8; ++j) v[j] = *(const shortx8*)(src + g * 64 + j * 8);
#pragma unroll
            for (int j = 0; j < 8; ++j) *(shortx8*)(dst + g * 64 + j * 8) = v[j];
        }
    }

    int wm = (wid & 1) * 64, wn = (wid >> 1) * 64;
    const short* bbase[4];
#pragma unroll
    for (int nt = 0; nt < 4; ++nt)
        bbase[nt] = wot + (size_t)(wn + nt * 16 + l15) * 256 + quad * 8;

    shortx8 b0[4], b1[4];
#pragma unroll
    for (int nt = 0; nt < 4; ++nt) b0[nt] = *(const shortx8*)(bbase[nt] + 0);
#pragma unroll
    for (int nt = 0; nt < 4; ++nt) b1[nt] = *(const shortx8*)(bbase[nt] + 32);

    __syncthreads();

    for (int t = 0; t < 2; ++t) {
        floatx4 acc[4][4];
#pragma unroll
        for (int mt = 0; mt < 4; ++mt)
#pragma unroll
            for (int nt = 0; nt < 4; ++nt) acc[mt][nt] = (floatx4){0.f, 0.f, 0.f, 0.f};
#pragma unroll
        for (int kt = 0; kt < 8; ++kt) {
            int u = t * 8 + kt + 2;
            shortx8 bn[4];
            if (u < 16) {
                int tn = u >> 3, kn = u & 7;
#pragma unroll
                for (int nt = 0; nt < 4; ++nt)
                    bn[nt] = *(const shortx8*)(bbase[nt] + tn * 32768 + kn * 32);
            }
            shortx8 af[4];
#pragma unroll
            for (int mt = 0; mt < 4; ++mt)
                af[mt] = *(const shortx8*)&As[(wm + mt * 16 + l15) * 264 + kt * 32 + quad * 8];
#pragma unroll
            for (int mt = 0; mt < 4; ++mt)
#pragma unroll
                for (int nt = 0; nt < 4; ++nt)
                    acc[mt][nt] = __builtin_amdgcn_mfma_f32_16x16x32_bf16(af[mt], b0[nt], acc[mt][nt], 0, 0, 0);
#pragma unroll
            for (int nt = 0; nt < 4; ++nt) { b0[nt] = b1[nt]; b1[nt] = bn[nt]; }
        }
        float biasv[4];
#pragma unroll
        for (int nt = 0; nt < 4; ++nt) biasv[nt] = bo[t * 128 + wn + nt * 16 + l15];
#pragma unroll
        for (int mt = 0; mt < 4; ++mt)
#pragma unroll
            for (int nt = 0; nt < 4; ++nt)
#pragma unroll
                for (int reg = 0; reg < 4; ++reg) {
                    int row = bm * 128 + wm + mt * 16 + quad * 4 + reg;
                    int col = t * 128 + wn + nt * 16 + l15;
                    out[(size_t)row2pix(row) * 256 + col] = acc[mt][nt][reg] + biasv[nt];
                }
    }
}

// ---------------- launch ----------------
extern "C" void kernel_launch(void* const* d_in, const int* in_sizes, int n_in,
                              void* d_out, int out_size, void* d_ws, size_t ws_size,
                              hipStream_t stream) {
    const float* x  = (const float*)d_in[0];
    const float* Wq = (const float*)d_in[1];
    const float* bq = (const float*)d_in[2];
    const float* Wk = (const float*)d_in[3];
    const float* bk = (const float*)d_in[4];
    const float* Wv = (const float*)d_in[5];
    const float* bv = (const float*)d_in[6];
    const float* Wo = (const float*)d_in[7];
    const float* bo = (const float*)d_in[8];
    const float* ls = (const float*)d_in[9];
    const float* w1 = (const float*)d_in[10];
    const float* b1 = (const float*)d_in[11];
    const float* w2 = (const float*)d_in[12];

    char* ws = (char*)d_ws;
    short* wqkv_t = (short*)(ws + 0);
    short* wo_t   = (short*)(ws + 393216);
    float* bias8  = (float*)(ws + 524288);
    float* scale  = (float*)(ws + 655360);
    float* b225g  = (float*)(ws + 786432);
    short* qkv    = (short*)(ws + 1048576);
    short* aout   = (short*)(ws + 101711872);
    float* out    = (float*)d_out;

    hipLaunchKernelGGL(wtrans, dim3(8, 8, 4), dim3(32, 8), 0, stream, Wq, Wk, Wv, Wo, wqkv_t, wo_t);
    hipLaunchKernelGGL(bias_mlp, dim3(225), dim3(256), 0, stream, ls, w1, b1, w2, b225g, scale);
    hipLaunchKernelGGL(bias_expand, dim3(128), dim3(256), 0, stream, b225g, bias8);
    hipLaunchKernelGGL(qkv_gemm, dim3(512), dim3(256), 0, stream, x, wqkv_t, bq, bk, bv, qkv);
    hipLaunchKernelGGL(attn_kernel, dim3(1024), dim3(256), 0, stream, qkv, bias8, scale, aout);
    hipLaunchKernelGGL(oproj_gemm, dim3(512), dim3(256), 0, stream, aout, wo_t, bo, out);
}

// Round 5
// 248.266 us; speedup vs baseline: 1.2401x; 1.2401x over previous
//
#include <hip/hip_runtime.h>
#include <hip/hip_bf16.h>

typedef float floatx4 __attribute__((ext_vector_type(4)));
typedef short shortx8 __attribute__((ext_vector_type(8)));
typedef short shortx4 __attribute__((ext_vector_type(4)));

#define CFENCE() asm volatile("" ::: "memory")

__device__ __forceinline__ float bf2f(short s) {
    union { unsigned u; float f; } cv;
    cv.u = ((unsigned)(unsigned short)s) << 16;
    return cv.f;
}
__device__ __forceinline__ short f2bf(float f) {
    union { float f; unsigned u; } cv; cv.f = f;
    unsigned r = (cv.u + 0x7fffu + ((cv.u >> 16) & 1u)) >> 16;
    return (short)r;
}

// ---------------- K0a: weights -> bf16 fragment-major layout ----------------
// wqkv_f: 384 frags (n16 0..47, kt 0..7), each 64 lanes x 8 shorts contiguous (1KB)
// wo_f:   128 frags (n16 0..15, kt 0..7)
// frag element: B[n = n16*16 + (lane&15)][k = kt*32 + (lane>>4)*8 + j]
__global__ __launch_bounds__(256) void wtrans(const float* __restrict__ Wq,
                                              const float* __restrict__ Wk,
                                              const float* __restrict__ Wv,
                                              const float* __restrict__ Wo,
                                              short* __restrict__ wqkv_f,
                                              short* __restrict__ wo_f) {
    int gtid = blockIdx.x * 256 + threadIdx.x;
    int f = gtid >> 6, lane = gtid & 63;
    int quad = lane >> 4, l15 = lane & 15;
    if (f < 384) {
        int n16 = f >> 3, kt = f & 7;
        int n = n16 * 16 + l15, z = n >> 8, ncol = n & 255;
        const float* src = (z == 0) ? Wq : (z == 1) ? Wk : Wv;
        shortx8 s;
#pragma unroll
        for (int j = 0; j < 8; ++j)
            s[j] = f2bf(src[(size_t)(kt * 32 + quad * 8 + j) * 256 + ncol]);
        *(shortx8*)(wqkv_f + (size_t)f * 512 + lane * 8) = s;
    } else {
        int f2 = f - 384;
        int n16 = f2 >> 3, kt = f2 & 7;
        int n = n16 * 16 + l15;
        shortx8 s;
#pragma unroll
        for (int j = 0; j < 8; ++j)
            s[j] = f2bf(Wo[(size_t)(kt * 32 + quad * 8 + j) * 256 + n]);
        *(shortx8*)(wo_f + (size_t)f2 * 512 + lane * 8) = s;
    }
}

// ---------------- K0b: CPB MLP, one block per table entry ----------------
__device__ __forceinline__ float sgnlog(float x) {
    return copysignf(__log2f(fabsf(x) + 1.f) / 3.f, x);
}
__global__ __launch_bounds__(256) void bias_mlp(const float* __restrict__ ls,
                                                const float* __restrict__ w1,
                                                const float* __restrict__ b1,
                                                const float* __restrict__ w2,
                                                float* __restrict__ b225g,
                                                float* __restrict__ scaleOut) {
    int e = blockIdx.x;
    int tid = threadIdx.x, lane = tid & 63, wid = tid >> 6;
    if (e == 0 && tid < 8) scaleOut[tid] = expf(fminf(ls[tid], 4.6051701859880914f));
    int dh = e / 15 - 7, dw = e % 15 - 7;
    float t0 = sgnlog(8.f * (float)dh / 7.f);
    float t1 = sgnlog(8.f * (float)dw / 7.f);
    float acc[8];
#pragma unroll
    for (int j = 0; j < 8; ++j) acc[j] = 0.f;
#pragma unroll
    for (int s = 0; s < 2; ++s) {
        int hsm = tid + s * 256;
        float hid = fmaxf(0.f, t0 * w1[hsm] + t1 * w1[512 + hsm] + b1[hsm]);
#pragma unroll
        for (int j = 0; j < 8; ++j) acc[j] += hid * w2[hsm * 8 + j];
    }
#pragma unroll
    for (int off = 1; off < 64; off <<= 1)
#pragma unroll
        for (int j = 0; j < 8; ++j) acc[j] += __shfl_xor(acc[j], off, 64);
    __shared__ float red[4][8];
    if (lane == 0)
#pragma unroll
        for (int j = 0; j < 8; ++j) red[wid][j] = acc[j];
    __syncthreads();
    if (tid < 8)
        b225g[e * 8 + tid] = red[0][tid] + red[1][tid] + red[2][tid] + red[3][tid];
}

// ---------------- K0c: expand to per-head 64x64 bias ----------------
__global__ __launch_bounds__(256) void bias_expand(const float* __restrict__ b225g,
                                                   float* __restrict__ bias8) {
    int f = blockIdx.x * 256 + threadIdx.x;
    int h = f >> 12, ij = f & 4095, i = ij >> 6, j = ij & 63;
    int dh = (i >> 3) - (j >> 3), dw = (i & 7) - (j & 7);
    int e = (dh + 7) * 15 + (dw + 7);
    float v = b225g[e * 8 + h];
    bias8[f] = 16.f / (1.f + expf(-v));
}

// token row -> pixel (roll by +4 both ways, same map fwd/bwd)
__device__ __forceinline__ int row2pix(int row) {
    int w = row >> 6, t = row & 63;
    int b = w >> 6, wi = (w >> 3) & 7, wj = w & 7;
    int hh = (wi * 8 + (t >> 3) + 4) & 63;
    int ww = (wj * 8 + (t & 7) + 4) & 63;
    return (b * 64 + hh) * 64 + ww;
}

// ---------------- K1: QKV projection; A LDS-resident, B coalesced frag loads, 1 barrier ----------------
// output layout qkv2: [win][h][q|k|v][tok 64][d 32]  (2048 shorts per (win,h,qi) slab)
__global__ __launch_bounds__(256, 2) void qkv_gemm(const float* __restrict__ x,
                                                   const short* __restrict__ wf,
                                                   const float* __restrict__ bq,
                                                   const float* __restrict__ bk_,
                                                   const float* __restrict__ bv,
                                                   short* __restrict__ qkv2) {
    __shared__ __align__(16) short As[128 * 264];
    int tid = threadIdx.x, lane = tid & 63, wid = tid >> 6;
    int quad = lane >> 4, l15 = lane & 15;
    int bm = blockIdx.x;

    // ---- stage A once: 128 rows x 256 k, fp32 gather -> bf16 LDS ----
    {
        int r = tid >> 1, half = tid & 1;
        const float* src = x + (size_t)row2pix(bm * 128 + r) * 256 + half * 128;
        short* dst = &As[r * 264 + half * 128];
#pragma unroll
        for (int g = 0; g < 4; ++g) {
            float4 v[8];
#pragma unroll
            for (int j = 0; j < 8; ++j) v[j] = *(const float4*)(src + g * 32 + j * 4);
#pragma unroll
            for (int j = 0; j < 4; ++j) {
                shortx8 s;
#pragma unroll
                for (int q2 = 0; q2 < 2; ++q2) {
                    float4 f = v[j * 2 + q2];
                    s[q2 * 4 + 0] = f2bf(f.x); s[q2 * 4 + 1] = f2bf(f.y);
                    s[q2 * 4 + 2] = f2bf(f.z); s[q2 * 4 + 3] = f2bf(f.w);
                }
                *(shortx8*)(dst + g * 32 + j * 8) = s;
            }
        }
    }

    int wm = (wid & 1) * 64, wnq = (wid >> 1);  // wn = wnq*64
    // frag address: wf + ((t*8 + wnq*4 + nt)*8 + kt)*512 + lane*8
    const short* bbase = wf + (size_t)wnq * 4 * 8 * 512 + lane * 8;

    shortx8 b0[4], b1[4];
#pragma unroll
    for (int nt = 0; nt < 4; ++nt)
        b0[nt] = *(const shortx8*)(bbase + ((size_t)nt * 8 + 0) * 512);
#pragma unroll
    for (int nt = 0; nt < 4; ++nt)
        b1[nt] = *(const shortx8*)(bbase + ((size_t)nt * 8 + 1) * 512);

    __syncthreads();  // the only barrier

    for (int t = 0; t < 6; ++t) {
        floatx4 acc[4][4];
#pragma unroll
        for (int mt = 0; mt < 4; ++mt)
#pragma unroll
            for (int nt = 0; nt < 4; ++nt) acc[mt][nt] = (floatx4){0.f, 0.f, 0.f, 0.f};
#pragma unroll
        for (int kt = 0; kt < 8; ++kt) {
            int u = t * 8 + kt + 2;
            if (u > 47) u = 46;                 // clamp: redundant tail loads, never used
            int tn = u >> 3, kn = u & 7;
            shortx8 bn[4];
#pragma unroll
            for (int nt = 0; nt < 4; ++nt)
                bn[nt] = *(const shortx8*)(bbase + ((size_t)(tn * 8 + wnq * 4 + nt) * 8 + kn) * 512 - (size_t)wnq * 4 * 8 * 512 + 0);
            shortx8 af[4];
#pragma unroll
            for (int mt = 0; mt < 4; ++mt)
                af[mt] = *(const shortx8*)&As[(wm + mt * 16 + l15) * 264 + kt * 32 + quad * 8];
#pragma unroll
            for (int mt = 0; mt < 4; ++mt)
#pragma unroll
                for (int nt = 0; nt < 4; ++nt)
                    acc[mt][nt] = __builtin_amdgcn_mfma_f32_16x16x32_bf16(af[mt], b0[nt], acc[mt][nt], 0, 0, 0);
#pragma unroll
            for (int nt = 0; nt < 4; ++nt) { b0[nt] = b1[nt]; b1[nt] = bn[nt]; }
        }
        // epilogue: bias + store into per-(win,head) layout
        float biasv[4];
        int colb[4];
#pragma unroll
        for (int nt = 0; nt < 4; ++nt) {
            int col = t * 128 + wnq * 64 + nt * 16 + l15;
            colb[nt] = col;
            biasv[nt] = (col < 256) ? bq[col] : (col < 512) ? bk_[col - 256] : bv[col - 512];
        }
#pragma unroll
        for (int mt = 0; mt < 4; ++mt)
#pragma unroll
            for (int reg = 0; reg < 4; ++reg) {
                int row = bm * 128 + wm + mt * 16 + quad * 4 + reg;
                int win = row >> 6, tok = row & 63;
                size_t rb = (size_t)win * 49152 + tok * 32;
#pragma unroll
                for (int nt = 0; nt < 4; ++nt) {
                    int col = colb[nt];
                    int qi = col >> 8, h = (col >> 5) & 7, d = col & 31;
                    qkv2[rb + (h * 3 + qi) * 2048 + d] = f2bf(acc[mt][nt][reg] + biasv[nt]);
                }
            }
    }
}

// ---------------- K3: per-window attention (wave-private LDS, no barriers) ----------------
__device__ __forceinline__ int regid(int t, int wi, int wj) {
    int a = (wi < 7) ? 0 : (((t >> 3) < 4) ? 1 : 2);
    int b = (wj < 7) ? 0 : (((t & 7) < 4) ? 1 : 2);
    return a * 3 + b;
}

__global__ __launch_bounds__(256, 2) void attn_kernel(const short* __restrict__ qkv2,
                                                      const float* __restrict__ bias8,
                                                      const float* __restrict__ scale,
                                                      short* __restrict__ aout) {
    __shared__ __align__(16) short lds[4 * 8192];
    int tid = threadIdx.x, lane = tid & 63, wid = tid >> 6;
    int quad = lane >> 4, l15 = lane & 15;
    int win = blockIdx.x;
    int wi = (win >> 3) & 7, wj = win & 7;
    bool need_mask = (wi == 7) || (wj == 7);
    short* qn = &lds[wid * 8192];
    short* kn = qn + 3584;
    short* P = qn;
    short* vt = qn + 5632;

    for (int hi = 0; hi < 2; ++hi) {
        int h = wid + hi * 4;
        float sc = scale[h];
        const short* base = qkv2 + (size_t)(win * 8 + h) * 3 * 2048;
        shortx8 qraw[4], kraw[4], vraw[4];
#pragma unroll
        for (int c2 = 0; c2 < 4; ++c2) {
            qraw[c2] = *(const shortx8*)(base + lane * 32 + c2 * 8);
            kraw[c2] = *(const shortx8*)(base + 2048 + lane * 32 + c2 * 8);
            vraw[c2] = *(const shortx8*)(base + 4096 + lane * 32 + c2 * 8);
        }
        float qs = 0.f, ks2 = 0.f;
#pragma unroll
        for (int c2 = 0; c2 < 4; ++c2)
#pragma unroll
            for (int j = 0; j < 8; ++j) {
                float f = bf2f(qraw[c2][j]); qs += f * f;
                float g = bf2f(kraw[c2][j]); ks2 += g * g;
            }
        float qr = sc / fmaxf(sqrtf(qs), 1e-12f);
        float kr = 1.f / fmaxf(sqrtf(ks2), 1e-12f);
        CFENCE();
#pragma unroll
        for (int c2 = 0; c2 < 4; ++c2) {
            shortx8 oq, ok;
#pragma unroll
            for (int j = 0; j < 8; ++j) {
                oq[j] = f2bf(bf2f(qraw[c2][j]) * qr);
                ok[j] = f2bf(bf2f(kraw[c2][j]) * kr);
            }
            *(shortx8*)&qn[lane * 56 + c2 * 8] = oq;
            *(shortx8*)&kn[lane * 56 + c2 * 8] = ok;
        }
        CFENCE();
        shortx8 aq[4], bkf[4];
#pragma unroll
        for (int mt = 0; mt < 4; ++mt)
            aq[mt] = *(const shortx8*)&qn[(mt * 16 + l15) * 56 + quad * 8];
#pragma unroll
        for (int nt = 0; nt < 4; ++nt)
            bkf[nt] = *(const shortx8*)&kn[(nt * 16 + l15) * 56 + quad * 8];
        floatx4 S[4][4];
#pragma unroll
        for (int mt = 0; mt < 4; ++mt)
#pragma unroll
            for (int nt = 0; nt < 4; ++nt) {
                floatx4 z = {0.f, 0.f, 0.f, 0.f};
                S[mt][nt] = __builtin_amdgcn_mfma_f32_16x16x32_bf16(aq[mt], bkf[nt], z, 0, 0, 0);
            }
        const float* bh = bias8 + (h << 12);
        float bound = sc + 16.5f;
        int jid[4];
        if (need_mask) {
#pragma unroll
            for (int nt = 0; nt < 4; ++nt) jid[nt] = regid(nt * 16 + l15, wi, wj);
        }
        float rs[4][4];
#pragma unroll
        for (int mt = 0; mt < 4; ++mt)
#pragma unroll
            for (int reg = 0; reg < 4; ++reg) {
                int i = mt * 16 + quad * 4 + reg;
                int iid = need_mask ? regid(i, wi, wj) : 0;
                float rowsum = 0.f;
#pragma unroll
                for (int nt = 0; nt < 4; ++nt) {
                    int j = nt * 16 + l15;
                    float v = S[mt][nt][reg] + bh[i * 64 + j];
                    if (need_mask && iid != jid[nt]) v -= 100.f;
                    float p = __expf(v - bound);
                    S[mt][nt][reg] = p;
                    rowsum += p;
                }
                rowsum += __shfl_xor(rowsum, 1, 64);
                rowsum += __shfl_xor(rowsum, 2, 64);
                rowsum += __shfl_xor(rowsum, 4, 64);
                rowsum += __shfl_xor(rowsum, 8, 64);
                rs[mt][reg] = 1.f / rowsum;
            }
        CFENCE();
#pragma unroll
        for (int mt = 0; mt < 4; ++mt)
#pragma unroll
            for (int nt = 0; nt < 4; ++nt)
#pragma unroll
                for (int reg = 0; reg < 4; ++reg)
                    P[(mt * 16 + quad * 4 + reg) * 88 + nt * 16 + l15] = f2bf(S[mt][nt][reg]);
#pragma unroll
        for (int c2 = 0; c2 < 4; ++c2)
#pragma unroll
            for (int j = 0; j < 8; ++j)
                vt[(c2 * 8 + j) * 72 + lane] = vraw[c2][j];
        CFENCE();
        floatx4 O[4][2];
#pragma unroll
        for (int mt = 0; mt < 4; ++mt)
#pragma unroll
            for (int nt = 0; nt < 2; ++nt) O[mt][nt] = (floatx4){0.f, 0.f, 0.f, 0.f};
#pragma unroll
        for (int ks = 0; ks < 2; ++ks) {
            shortx8 pa[4], vb[2];
#pragma unroll
            for (int mt = 0; mt < 4; ++mt)
                pa[mt] = *(const shortx8*)&P[(mt * 16 + l15) * 88 + ks * 32 + quad * 8];
#pragma unroll
            for (int nt = 0; nt < 2; ++nt)
                vb[nt] = *(const shortx8*)&vt[(nt * 16 + l15) * 72 + ks * 32 + quad * 8];
#pragma unroll
            for (int mt = 0; mt < 4; ++mt)
#pragma unroll
                for (int nt = 0; nt < 2; ++nt)
                    O[mt][nt] = __builtin_amdgcn_mfma_f32_16x16x32_bf16(pa[mt], vb[nt], O[mt][nt], 0, 0, 0);
        }
#pragma unroll
        for (int mt = 0; mt < 4; ++mt)
#pragma unroll
            for (int nt = 0; nt < 2; ++nt)
#pragma unroll
                for (int reg = 0; reg < 4; ++reg) {
                    int i = mt * 16 + quad * 4 + reg;
                    int d = nt * 16 + l15;
                    aout[(size_t)(win * 64 + i) * 256 + (h << 5) + d] =
                        f2bf(O[mt][nt][reg] * rs[mt][reg]);
                }
    }
}

// ---------------- K4: output projection; A LDS-resident, B coalesced frag loads ----------------
__global__ __launch_bounds__(256, 2) void oproj_gemm(const short* __restrict__ ao,
                                                     const short* __restrict__ wof,
                                                     const float* __restrict__ bo,
                                                     float* __restrict__ out) {
    __shared__ __align__(16) short As[128 * 264];
    int tid = threadIdx.x, lane = tid & 63, wid = tid >> 6;
    int quad = lane >> 4, l15 = lane & 15;
    int bm = blockIdx.x;

    {
        int r = tid >> 1, half = tid & 1;
        const short* src = ao + (size_t)(bm * 128 + r) * 256 + half * 128;
        short* dst = &As[r * 264 + half * 128];
#pragma unroll
        for (int g = 0; g < 2; ++g) {
            shortx8 v[8];
#pragma unroll
            for (int j = 0; j < 8; ++j) v[j] = *(const shortx8*)(src + g * 64 + j * 8);
#pragma unroll
            for (int j = 0; j < 8; ++j) *(shortx8*)(dst + g * 64 + j * 8) = v[j];
        }
    }

    int wm = (wid & 1) * 64, wnq = (wid >> 1);
    const short* bbase = wof + (size_t)wnq * 4 * 8 * 512 + lane * 8;

    shortx8 b0[4], b1[4];
#pragma unroll
    for (int nt = 0; nt < 4; ++nt)
        b0[nt] = *(const shortx8*)(bbase + ((size_t)nt * 8 + 0) * 512);
#pragma unroll
    for (int nt = 0; nt < 4; ++nt)
        b1[nt] = *(const shortx8*)(bbase + ((size_t)nt * 8 + 1) * 512);

    __syncthreads();

    for (int t = 0; t < 2; ++t) {
        floatx4 acc[4][4];
#pragma unroll
        for (int mt = 0; mt < 4; ++mt)
#pragma unroll
            for (int nt = 0; nt < 4; ++nt) acc[mt][nt] = (floatx4){0.f, 0.f, 0.f, 0.f};
#pragma unroll
        for (int kt = 0; kt < 8; ++kt) {
            int u = t * 8 + kt + 2;
            if (u > 15) u = 14;
            int tn = u >> 3, kn = u & 7;
            shortx8 bn[4];
#pragma unroll
            for (int nt = 0; nt < 4; ++nt)
                bn[nt] = *(const shortx8*)(bbase + ((size_t)(tn * 8 + nt) * 8 + kn) * 512);
            shortx8 af[4];
#pragma unroll
            for (int mt = 0; mt < 4; ++mt)
                af[mt] = *(const shortx8*)&As[(wm + mt * 16 + l15) * 264 + kt * 32 + quad * 8];
#pragma unroll
            for (int mt = 0; mt < 4; ++mt)
#pragma unroll
                for (int nt = 0; nt < 4; ++nt)
                    acc[mt][nt] = __builtin_amdgcn_mfma_f32_16x16x32_bf16(af[mt], b0[nt], acc[mt][nt], 0, 0, 0);
#pragma unroll
            for (int nt = 0; nt < 4; ++nt) { b0[nt] = b1[nt]; b1[nt] = bn[nt]; }
        }
        float biasv[4];
#pragma unroll
        for (int nt = 0; nt < 4; ++nt) biasv[nt] = bo[t * 128 + wnq * 64 + nt * 16 + l15];
#pragma unroll
        for (int mt = 0; mt < 4; ++mt)
#pragma unroll
            for (int nt = 0; nt < 4; ++nt)
#pragma unroll
                for (int reg = 0; reg < 4; ++reg) {
                    int row = bm * 128 + wm + mt * 16 + quad * 4 + reg;
                    int col = t * 128 + wnq * 64 + nt * 16 + l15;
                    out[(size_t)row2pix(row) * 256 + col] = acc[mt][nt][reg] + biasv[nt];
                }
    }
}

// ---------------- launch ----------------
extern "C" void kernel_launch(void* const* d_in, const int* in_sizes, int n_in,
                              void* d_out, int out_size, void* d_ws, size_t ws_size,
                              hipStream_t stream) {
    const float* x  = (const float*)d_in[0];
    const float* Wq = (const float*)d_in[1];
    const float* bq = (const float*)d_in[2];
    const float* Wk = (const float*)d_in[3];
    const float* bk = (const float*)d_in[4];
    const float* Wv = (const float*)d_in[5];
    const float* bv = (const float*)d_in[6];
    const float* Wo = (const float*)d_in[7];
    const float* bo = (const float*)d_in[8];
    const float* ls = (const float*)d_in[9];
    const float* w1 = (const float*)d_in[10];
    const float* b1 = (const float*)d_in[11];
    const float* w2 = (const float*)d_in[12];

    char* ws = (char*)d_ws;
    short* wqkv_f = (short*)(ws + 0);           //   393,216 B
    short* wo_f   = (short*)(ws + 393216);      //   131,072 B
    float* bias8  = (float*)(ws + 524288);      //   131,072 B
    float* scale  = (float*)(ws + 655360);      //        32 B
    float* b225g  = (float*)(ws + 786432);      //     7,200 B
    short* qkv2   = (short*)(ws + 1048576);     // 100,663,296 B
    short* aout   = (short*)(ws + 101711872);   //  33,554,432 B
    float* out    = (float*)d_out;

    hipLaunchKernelGGL(wtrans, dim3(128), dim3(256), 0, stream, Wq, Wk, Wv, Wo, wqkv_f, wo_f);
    hipLaunchKernelGGL(bias_mlp, dim3(225), dim3(256), 0, stream, ls, w1, b1, w2, b225g, scale);
    hipLaunchKernelGGL(bias_expand, dim3(128), dim3(256), 0, stream, b225g, bias8);
    hipLaunchKernelGGL(qkv_gemm, dim3(512), dim3(256), 0, stream, x, wqkv_f, bq, bk, bv, qkv2);
    hipLaunchKernelGGL(attn_kernel, dim3(1024), dim3(256), 0, stream, qkv2, bias8, scale, aout);
    hipLaunchKernelGGL(oproj_gemm, dim3(512), dim3(256), 0, stream, aout, wo_f, bo, out);
}